// Round 15
// baseline (11392.723 us; speedup 1.0000x reference)
//
#include <hip/hip_runtime.h>
#include <math.h>

#define BB 64
#define TT 128
#define DBX 256
#define IND 264
#define HS 512
#define NH 4
#define MMM 128
#define AAA 2048
#define PPH 390
#define NCOLS (DBX + NH*PPH)   // 2072
#define KSPL 8                 // k1 split-K: 8 x 161
#define KCH  161
#define EPSF 1e-8f

__device__ __forceinline__ float sigmf(float x){ return 1.0f/(1.0f+expf(-x)); }
__device__ __forceinline__ float softplusf(float x){ return (x > 20.0f) ? x : log1pf(expf(x)); }

// ---------------- init ----------------
__global__ void k_init(float* __restrict__ hT, float* __restrict__ readT,
                       float* __restrict__ wt0, float* __restrict__ mem){
  int i = blockIdx.x*blockDim.x + threadIdx.x;
  int stride = gridDim.x*blockDim.x;
  for (int idx=i; idx<BB*MMM*AAA; idx+=stride) mem[idx]=0.01f;
  for (int idx=i; idx<HS*BB; idx+=stride){ hT[idx]=1.0f; readT[idx]=0.01f; }
  for (int idx=i; idx<BB*NH*AAA; idx+=stride) wt0[idx] = ((idx & (AAA-1))==0)?1.0f:0.0f;
}

// ---------------- transpose x[b][t][i] -> xT[t*IND+i][b] (once) ----------------
__global__ __launch_bounds__(256) void k_tx(const float* __restrict__ x, float* __restrict__ xT){
  int b = blockIdx.x;
  for (int f = threadIdx.x; f < TT*IND; f += 256)
    xT[(size_t)f*BB + b] = x[(size_t)b*TT*IND + f];
}

// ---------------- k1: split-K partial GEMM  hpart[ks][j][b] ----------------
__global__ __launch_bounds__(256) void k1_state(
    const float* __restrict__ xT, const float* __restrict__ Wst,
    const float* __restrict__ hTp, const float* __restrict__ readTp,
    float* __restrict__ hpart, float* __restrict__ wcsum, int t)
{
  int tid = threadIdx.x, wave = tid>>6, lane = tid&63;
  int ks = blockIdx.y;
  int j0 = blockIdx.x*16 + wave*4;
  if (blockIdx.x==0 && ks==0){
    wcsum[tid] = 0.0f;   // BB*NH == 256
  }
  float a0=0,a1=0,a2=0,a3=0;
  int k0 = ks*KCH, kend = k0+KCH;

  #define K1STEP(AEXPR) { float aV=(AEXPR); \
      float4 wv = *(const float4*)(Wst + (size_t)k*HS + j0); \
      a0 += aV*wv.x; a1 += aV*wv.y; a2 += aV*wv.z; a3 += aV*wv.w; }

  {int s = k0, e = kend<IND?kend:IND;
   #pragma unroll 4
   for (int k=s;k<e;++k) K1STEP(xT[((size_t)t*IND + k)*BB + lane]); }
  {int s = k0>IND?k0:IND, e = kend<(IND+HS)?kend:(IND+HS);
   #pragma unroll 4
   for (int k=s;k<e;++k) K1STEP(hTp[(k-IND)*BB + lane]); }
  {int s = k0>(IND+HS)?k0:(IND+HS), e = kend;
   #pragma unroll 4
   for (int k=s;k<e;++k) K1STEP(readTp[(k-IND-HS)*BB + lane]); }
  #undef K1STEP

  float* hp = hpart + (size_t)ks*HS*BB + (size_t)j0*BB + lane;
  hp[0]    = a0;
  hp[BB]   = a1;
  hp[2*BB] = a2;
  hp[3*BB] = a3;
}

// ---------------- k2h: reduce split-K partials -> h = sigmoid(. + b) ----------------
__global__ __launch_bounds__(512) void k2h(
    const float* __restrict__ hpart, const float* __restrict__ bst, float* __restrict__ hTn)
{
  int idx = blockIdx.x*512 + threadIdx.x;   // 64 blocks x 512 = 32768 = HS*BB
  float v = 0.0f;
  #pragma unroll
  for (int ks=0; ks<KSPL; ++ks) v += hpart[(size_t)ks*HS*BB + idx];
  hTn[idx] = sigmf(v + bst[idx>>6]);
}

// ---------------- k2: out/upd GEMM, split-K across 4 waves, + transforms ----------------
__global__ __launch_bounds__(256) void k2_outupd(
    const float* __restrict__ hTn,
    const float* __restrict__ Wout, const float* __restrict__ bout,
    const float* __restrict__ Wupd, const float* __restrict__ bupd,
    float* __restrict__ out,
    float* __restrict__ kvec_t, float* __restrict__ beta, float* __restrict__ gbuf,
    float* __restrict__ gam, float* __restrict__ shraw,
    float* __restrict__ erase, float* __restrict__ addb, int t)
{
  __shared__ float part[4][8][BB];
  int tid = threadIdx.x, ks = tid>>6, lane = tid&63;
  int c0 = blockIdx.x*8;
  bool isout = (c0 < DBX);
  size_t strd = isout ? (size_t)DBX : (size_t)(NH*PPH);
  const float* wbase = isout ? (Wout + c0) : (Wupd + (c0 - DBX));
  bool valid = (c0 < NCOLS);

  float acc[8] = {0,0,0,0,0,0,0,0};
  if (valid){
    int k0 = ks*128;
    #pragma unroll 4
    for (int k=k0; k<k0+128; ++k){
      float a = hTn[k*BB + lane];
      const float4* w4 = (const float4*)(wbase + (size_t)k*strd);
      float4 wa = w4[0], wb = w4[1];
      acc[0]+=a*wa.x; acc[1]+=a*wa.y; acc[2]+=a*wa.z; acc[3]+=a*wa.w;
      acc[4]+=a*wb.x; acc[5]+=a*wb.y; acc[6]+=a*wb.z; acc[7]+=a*wb.w;
    }
  }
  #pragma unroll
  for (int u=0; u<8; ++u) part[ks][u][lane] = acc[u];
  __syncthreads();
  if (!valid) return;

  for (int idx=tid; idx<8*BB; idx+=256){
    int u = idx>>6, b = idx&63;
    int c = c0+u;
    float v = part[0][u][b] + part[1][u][b] + part[2][u][b] + part[3][u][b];
    if (isout){
      out[((size_t)b*TT + t)*DBX + c] = sigmf(v + bout[c]);
    } else {
      int u2 = c - DBX;
      int hh = u2 / PPH;
      int p  = u2 - hh*PPH;
      v += bupd[u2];
      if (p < MMM)            kvec_t[b*HS + p*NH + hh] = v;
      else if (p == MMM)      beta[b*NH+hh] = softplusf(v);
      else if (p == MMM+1)    gbuf[b*NH+hh] = sigmf(v);
      else if (p <  MMM+5)    shraw[(b*NH+hh)*3 + (p-(MMM+2))] = v;
      else if (p == MMM+5)    gam[b*NH+hh] = 1.0f + softplusf(v);
      else if (p <  2*MMM+6)  erase[b*HS + hh*MMM + (p-(MMM+6))] = sigmf(v);
      else                    addb[b*HS + hh*MMM + (p-(2*MMM+6))] = tanhf(v);
    }
  }
}

// ---------------- dots (fused): knorm + dot + mnorm + exp + wcsum ----------------
// grid (BB, 8), block 256. Thread owns column a = s*256+tid, loops all 128 m-rows.
__global__ __launch_bounds__(256) void k_dots(
    const float* __restrict__ mem, const float* __restrict__ kvec_t,
    const float* __restrict__ beta,
    float* __restrict__ ebuf, float* __restrict__ wcsum)
{
  int b = blockIdx.x, s = blockIdx.y, tid = threadIdx.x;
  __shared__ __align__(16) float kl[HS];    // [m*4+h]
  __shared__ float red[256];
  __shared__ float kn[NH], pb[NH];
  __shared__ float rsum[4*NH];
  kl[tid]     = kvec_t[b*HS + tid];
  kl[tid+256] = kvec_t[b*HS + 256 + tid];
  if (tid < NH) pb[tid] = beta[b*NH + tid];
  __syncthreads();
  red[tid] = kl[tid]*kl[tid] + kl[tid+256]*kl[tid+256];
  __syncthreads();
  #pragma unroll
  for (int off=128; off>=4; off>>=1){
    if (tid < off) red[tid] += red[tid+off];
    __syncthreads();
  }
  if (tid < NH) kn[tid] = sqrtf(red[tid]);
  __syncthreads();

  int a = s*256 + tid;
  const float* mp = mem + (size_t)b*MMM*AAA + a;
  const float4* k4 = (const float4*)kl;
  float d0=0,d1=0,d2=0,d3=0,n2=0;
  for (int mb=0; mb<MMM; mb+=16){
    float mv[16];
    #pragma unroll
    for (int u=0;u<16;++u) mv[u] = mp[(size_t)(mb+u)*AAA];
    #pragma unroll
    for (int u=0;u<16;++u){
      float4 kv = k4[mb+u];
      d0 += kv.x*mv[u]; d1 += kv.y*mv[u]; d2 += kv.z*mv[u]; d3 += kv.w*mv[u];
      n2 += mv[u]*mv[u];
    }
  }
  float mn = sqrtf(n2);
  float dd[NH] = {d0,d1,d2,d3};
  int wave = tid >> 6, lane = tid & 63;
  float e_r[NH];
  #pragma unroll
  for (int hh=0; hh<NH; ++hh){
    float sim = dd[hh]/(kn[hh]*mn + EPSF);
    float e = expf(pb[hh]*sim);
    e_r[hh] = e;
    ebuf[((size_t)(b*NH+hh))*AAA + a] = e;
  }
  #pragma unroll
  for (int hh=0; hh<NH; ++hh){
    float v = e_r[hh];
    #pragma unroll
    for (int off=32; off>0; off>>=1) v += __shfl_xor(v, off);
    if (lane==0) rsum[wave*NH+hh] = v;
  }
  __syncthreads();
  if (tid < NH){
    float s2 = rsum[tid] + rsum[NH+tid] + rsum[2*NH+tid] + rsum[3*NH+tid];
    atomicAdd(&wcsum[b*NH+tid], s2);
  }
}

// ---------------- updfin (fused): shift/sharpen + wt_new + mem update + read einsum ----------------
// grid (BB, 8), block 512 = 8 waves. Phase A-C: recompute shift per block (redundant x8,
// L2-hot), local wpsum (no atomics). Row phase: wave owns rows m0=my*8+wave, m1=m0+64.
__global__ __launch_bounds__(512) void k_updfin(
    float* __restrict__ mem, const float* __restrict__ ebuf,
    const float* __restrict__ wtp, float* __restrict__ wtn,
    const float* __restrict__ wcsum, const float* __restrict__ shraw,
    const float* __restrict__ gbuf, const float* __restrict__ gam,
    const float* __restrict__ erase, const float* __restrict__ addb,
    float* __restrict__ readTn)
{
  __shared__ __align__(16) float wgl[AAA*4];  // 32 KB: wg staged [a][h]
  __shared__ __align__(16) float wpl[AAA*4];  // 32 KB: wp -> wtn [a][h]
  __shared__ float sh[12], gg[4], gmm[4], wci[4], psr[8*4], wpsl[4];
  int b = blockIdx.x, my = blockIdx.y, tid = threadIdx.x;
  int wave = tid >> 6, lane = tid & 63;
  if (tid < 4){
    gg[tid]  = gbuf[b*NH+tid];
    gmm[tid] = gam[b*NH+tid];
    wci[tid] = 1.0f/wcsum[b*NH+tid];
    float s0 = shraw[(b*NH+tid)*3], s1 = shraw[(b*NH+tid)*3+1], s2 = shraw[(b*NH+tid)*3+2];
    float mx = fmaxf(s0, fmaxf(s1, s2));
    float e0 = expf(s0-mx), e1 = expf(s1-mx), e2 = expf(s2-mx);
    float inv = 1.0f/(e0+e1+e2);
    sh[tid*3] = e0*inv; sh[tid*3+1] = e1*inv; sh[tid*3+2] = e2*inv;
  }
  __syncthreads();
  // phase A: wg = g*e/wcsum + (1-g)*wt_prev  -> LDS (float4 writes)
  #pragma unroll
  for (int c4=0; c4<4; ++c4){
    int a = c4*512 + tid;
    float4 wg;
    wg.x = gg[0]*ebuf[((size_t)(b*NH+0))*AAA+a]*wci[0] + (1.0f-gg[0])*wtp[((size_t)(b*NH+0))*AAA+a];
    wg.y = gg[1]*ebuf[((size_t)(b*NH+1))*AAA+a]*wci[1] + (1.0f-gg[1])*wtp[((size_t)(b*NH+1))*AAA+a];
    wg.z = gg[2]*ebuf[((size_t)(b*NH+2))*AAA+a]*wci[2] + (1.0f-gg[2])*wtp[((size_t)(b*NH+2))*AAA+a];
    wg.w = gg[3]*ebuf[((size_t)(b*NH+3))*AAA+a]*wci[3] + (1.0f-gg[3])*wtp[((size_t)(b*NH+3))*AAA+a];
    ((float4*)wgl)[a] = wg;
  }
  __syncthreads();
  // phase B: shift + sharpen, accumulate local wpsum
  float ps0=0,ps1=0,ps2=0,ps3=0;
  const float4* wg4 = (const float4*)wgl;
  #pragma unroll
  for (int c4=0; c4<4; ++c4){
    int a = c4*512 + tid;
    int am1 = (a + AAA - 1) & (AAA-1);
    int ap1 = (a + 1) & (AAA-1);
    float4 w0 = wg4[a], wm = wg4[am1], wp_ = wg4[ap1];
    float p0 = powf(sh[0]*wp_.x + sh[1]*w0.x + sh[2]*wm.x + EPSF, gmm[0]);
    float p1 = powf(sh[3]*wp_.y + sh[4]*w0.y + sh[5]*wm.y + EPSF, gmm[1]);
    float p2 = powf(sh[6]*wp_.z + sh[7]*w0.z + sh[8]*wm.z + EPSF, gmm[2]);
    float p3 = powf(sh[9]*wp_.w + sh[10]*w0.w + sh[11]*wm.w + EPSF, gmm[3]);
    ((float4*)wpl)[a] = make_float4(p0,p1,p2,p3);
    ps0 += p0; ps1 += p1; ps2 += p2; ps3 += p3;
  }
  {
    float ps[4] = {ps0,ps1,ps2,ps3};
    #pragma unroll
    for (int h=0; h<4; ++h){
      float v = ps[h];
      #pragma unroll
      for (int off=32; off>0; off>>=1) v += __shfl_xor(v, off);
      if (lane==0) psr[wave*4+h] = v;
    }
    __syncthreads();
    if (tid < 4){
      float s = 0.0f;
      #pragma unroll
      for (int w=0; w<8; ++w) s += psr[w*4+tid];
      wpsl[tid] = 1.0f/s;
    }
    __syncthreads();
  }
  // phase C: normalize -> wtn (LDS in place; global for my==0)
  {
    float wi0=wpsl[0], wi1=wpsl[1], wi2=wpsl[2], wi3=wpsl[3];
    #pragma unroll
    for (int c4=0; c4<4; ++c4){
      int a = c4*512 + tid;
      float4 wv = ((const float4*)wpl)[a];
      wv.x *= wi0; wv.y *= wi1; wv.z *= wi2; wv.w *= wi3;
      ((float4*)wpl)[a] = wv;
      if (my == 0){
        wtn[((size_t)(b*NH+0))*AAA + a] = wv.x;
        wtn[((size_t)(b*NH+1))*AAA + a] = wv.y;
        wtn[((size_t)(b*NH+2))*AAA + a] = wv.z;
        wtn[((size_t)(b*NH+3))*AAA + a] = wv.w;
      }
    }
  }
  __syncthreads();
  // row phase: mem erase/add + read einsum (round-14 proven pattern)
  int m0 = my*8 + wave, m1 = m0 + 64;
  float er0[4], ad0[4], er1[4], ad1[4];
  #pragma unroll
  for (int h=0;h<4;++h){
    er0[h] = erase[b*HS + h*MMM + m0];
    ad0[h] = addb [b*HS + h*MMM + m0];
    er1[h] = erase[b*HS + h*MMM + m1];
    ad1[h] = addb [b*HS + h*MMM + m1];
  }
  float* row0 = mem + (size_t)b*MMM*AAA + (size_t)m0*AAA;
  float* row1 = mem + (size_t)b*MMM*AAA + (size_t)m1*AAA;
  const float4* wl4 = (const float4*)wpl;
  float r00=0,r01=0,r02=0,r03=0, r10=0,r11=0,r12=0,r13=0;
  #pragma unroll 4
  for (int it=0; it<32; ++it){
    int a = it*64 + lane;
    float mv0 = row0[a], mv1 = row1[a];
    float4 w4 = wl4[a];
    float et0 = (1.0f - er0[0]*w4.x)*(1.0f - er0[1]*w4.y)
              * (1.0f - er0[2]*w4.z)*(1.0f - er0[3]*w4.w);
    float at0 = ad0[0]*w4.x + ad0[1]*w4.y + ad0[2]*w4.z + ad0[3]*w4.w;
    float n0 = mv0*et0 + at0;
    row0[a] = n0;
    r00 += n0*w4.x; r01 += n0*w4.y; r02 += n0*w4.z; r03 += n0*w4.w;
    float et1 = (1.0f - er1[0]*w4.x)*(1.0f - er1[1]*w4.y)
              * (1.0f - er1[2]*w4.z)*(1.0f - er1[3]*w4.w);
    float at1 = ad1[0]*w4.x + ad1[1]*w4.y + ad1[2]*w4.z + ad1[3]*w4.w;
    float n1 = mv1*et1 + at1;
    row1[a] = n1;
    r10 += n1*w4.x; r11 += n1*w4.y; r12 += n1*w4.z; r13 += n1*w4.w;
  }
  float rr[2][NH] = {{r00,r01,r02,r03},{r10,r11,r12,r13}};
  #pragma unroll
  for (int q=0; q<2; ++q){
    #pragma unroll
    for (int hh=0; hh<NH; ++hh){
      float v = rr[q][hh];
      #pragma unroll
      for (int off=32; off>0; off>>=1) v += __shfl_xor(v, off);
      rr[q][hh] = v;
    }
  }
  if (lane == 0){
    #pragma unroll
    for (int hh=0; hh<NH; ++hh){
      readTn[(size_t)(hh*MMM+m0)*BB + b] = rr[0][hh];
      readTn[(size_t)(hh*MMM+m1)*BB + b] = rr[1][hh];
    }
  }
}

extern "C" void kernel_launch(void* const* d_in, const int* in_sizes, int n_in,
                              void* d_out, int out_size, void* d_ws, size_t ws_size,
                              hipStream_t stream){
  const float* x    = (const float*)d_in[0];
  const float* Wst  = (const float*)d_in[1];
  const float* bst  = (const float*)d_in[2];
  const float* Wout = (const float*)d_in[3];
  const float* bout = (const float*)d_in[4];
  const float* Wupd = (const float*)d_in[5];
  const float* bupd = (const float*)d_in[6];
  float* out = (float*)d_out;

  float* p = (float*)d_ws;
  float* hT     = p; p += 2*HS*BB;            // ping-pong h, [j][b]
  float* readT  = p; p += 2*HS*BB;            // ping-pong read, [(h,m)][b]
  float* hpart  = p; p += KSPL*HS*BB;         // split-K partials (1 MB)
  float* xT     = p; p += (size_t)TT*IND*BB;  // transposed x (8.65 MB)
  float* wtb    = p; p += 2*BB*NH*AAA;        // ping-pong wt (2 x 2 MB)
  float* mem    = p; p += (size_t)BB*MMM*AAA;
  float* kvec_t = p; p += BB*HS;
  float* beta   = p; p += BB*NH;
  float* gbuf   = p; p += BB*NH;
  float* gam    = p; p += BB*NH;
  float* shraw  = p; p += BB*NH*3;
  float* erase  = p; p += BB*HS;
  float* addb   = p; p += BB*HS;
  float* ebuf   = p; p += BB*NH*AAA;
  float* wcsum  = p; p += BB*NH;

  k_init<<<2048, 256, 0, stream>>>(hT, readT, wtb, mem);
  k_tx<<<BB, 256, 0, stream>>>(x, xT);
  for (int t=0; t<TT; ++t){
    const float* hTp = hT    + (t&1)*HS*BB;
    float* hTn       = hT    + ((t+1)&1)*HS*BB;
    const float* rTp = readT + (t&1)*HS*BB;
    float* rTn       = readT + ((t+1)&1)*HS*BB;
    const float* wtp = wtb   + (t&1)*BB*NH*AAA;
    float* wtn       = wtb   + ((t+1)&1)*BB*NH*AAA;
    k1_state<<<dim3(32,KSPL), 256, 0, stream>>>(xT, Wst, hTp, rTp, hpart, wcsum, t);
    k2h<<<64, 512, 0, stream>>>(hpart, bst, hTn);
    k2_outupd<<<dim3(259), 256, 0, stream>>>(hTn, Wout, bout, Wupd, bupd, out,
        kvec_t, beta, gbuf, gam, shraw, erase, addb, t);
    k_dots<<<dim3(BB,8), 256, 0, stream>>>(mem, kvec_t, beta, ebuf, wcsum);
    k_updfin<<<dim3(BB,8), 512, 0, stream>>>(mem, ebuf, wtp, wtn, wcsum, shraw,
        gbuf, gam, erase, addb, rTn);
  }
}

// Round 16
// 9774.699 us; speedup vs baseline: 1.1655x; 1.1655x over previous
//
#include <hip/hip_runtime.h>
#include <math.h>

#define BB 64
#define TT 128
#define DBX 256
#define IND 264
#define HS 512
#define NH 4
#define MMM 128
#define AAA 2048
#define PPH 390
#define NCOLS (DBX + NH*PPH)   // 2072
#define KTOT (IND + HS + HS)   // 1288
#define KSPL 16                // k1 split-K: 16 x 81
#define KCH  81
#define EPSF 1e-8f

__device__ __forceinline__ float sigmf(float x){ return 1.0f/(1.0f+expf(-x)); }
__device__ __forceinline__ float softplusf(float x){ return (x > 20.0f) ? x : log1pf(expf(x)); }

// ---------------- init ----------------
__global__ void k_init(float* __restrict__ hT, float* __restrict__ readT,
                       float* __restrict__ wt, float* __restrict__ mem){
  int i = blockIdx.x*blockDim.x + threadIdx.x;
  int stride = gridDim.x*blockDim.x;
  for (int idx=i; idx<BB*MMM*AAA; idx+=stride) mem[idx]=0.01f;
  for (int idx=i; idx<HS*BB; idx+=stride){ hT[idx]=1.0f; readT[idx]=0.01f; }
  for (int idx=i; idx<BB*NH*AAA; idx+=stride) wt[idx] = ((idx & (AAA-1))==0)?1.0f:0.0f;
}

// ---------------- transpose x[b][t][i] -> xT[t*IND+i][b] (once) ----------------
__global__ __launch_bounds__(256) void k_tx(const float* __restrict__ x, float* __restrict__ xT){
  int b = blockIdx.x;
  for (int f = threadIdx.x; f < TT*IND; f += 256)
    xT[(size_t)f*BB + b] = x[(size_t)b*TT*IND + f];
}

// ---------------- k1: split-K partial GEMM  hpart[ks][j][b], 16-way ----------------
__global__ __launch_bounds__(256) void k1_state(
    const float* __restrict__ xT, const float* __restrict__ Wst,
    const float* __restrict__ hTp, const float* __restrict__ readTp,
    float* __restrict__ hpart, float* __restrict__ wcsum, float* __restrict__ wpsum, int t)
{
  int tid = threadIdx.x, wave = tid>>6, lane = tid&63;
  int ks = blockIdx.y;
  int j0 = blockIdx.x*16 + wave*4;
  if (blockIdx.x==0 && ks==0){
    wcsum[tid] = 0.0f;   // BB*NH == 256
    wpsum[tid] = 0.0f;
  }
  float a0=0,a1=0,a2=0,a3=0;
  int k0 = ks*KCH, kend = k0+KCH;
  if (kend > KTOT) kend = KTOT;

  #define K1STEP(AEXPR) { float aV=(AEXPR); \
      float4 wv = *(const float4*)(Wst + (size_t)k*HS + j0); \
      a0 += aV*wv.x; a1 += aV*wv.y; a2 += aV*wv.z; a3 += aV*wv.w; }

  {int s = k0, e = kend<IND?kend:IND;
   #pragma unroll 4
   for (int k=s;k<e;++k) K1STEP(xT[((size_t)t*IND + k)*BB + lane]); }
  {int s = k0>IND?k0:IND, e = kend<(IND+HS)?kend:(IND+HS);
   #pragma unroll 4
   for (int k=s;k<e;++k) K1STEP(hTp[(k-IND)*BB + lane]); }
  {int s = k0>(IND+HS)?k0:(IND+HS), e = kend;
   #pragma unroll 4
   for (int k=s;k<e;++k) K1STEP(readTp[(k-IND-HS)*BB + lane]); }
  #undef K1STEP

  float* hp = hpart + (size_t)ks*HS*BB + (size_t)j0*BB + lane;
  hp[0]    = a0;
  hp[BB]   = a1;
  hp[2*BB] = a2;
  hp[3*BB] = a3;
}

// ---------------- k2h: reduce 16 split-K partials -> h = sigmoid(. + b) ----------------
__global__ __launch_bounds__(256) void k2h(
    const float* __restrict__ hpart, const float* __restrict__ bst, float* __restrict__ hTn)
{
  int idx = blockIdx.x*256 + threadIdx.x;   // 128 blocks x 256 = 32768 = HS*BB
  float v = 0.0f;
  #pragma unroll
  for (int ks=0; ks<KSPL; ++ks) v += hpart[(size_t)ks*HS*BB + idx];
  hTn[idx] = sigmf(v + bst[idx>>6]);
}

// ---------------- k2: out/upd GEMM, 4 cols/block, split-K across 4 waves ----------------
// grid 518 blocks (518*4 = 2072 = NCOLS; blocks 0..63 are Wout, no straddle)
__global__ __launch_bounds__(256) void k2_outupd(
    const float* __restrict__ hTn,
    const float* __restrict__ Wout, const float* __restrict__ bout,
    const float* __restrict__ Wupd, const float* __restrict__ bupd,
    float* __restrict__ out,
    float* __restrict__ kvec_t, float* __restrict__ beta, float* __restrict__ gbuf,
    float* __restrict__ gam, float* __restrict__ shraw,
    float* __restrict__ erase, float* __restrict__ addb, int t)
{
  __shared__ float part[4][4][BB];
  int tid = threadIdx.x, ks = tid>>6, lane = tid&63;
  int c0 = blockIdx.x*4;
  bool isout = (c0 < DBX);
  size_t strd = isout ? (size_t)DBX : (size_t)(NH*PPH);
  const float* wbase = isout ? (Wout + c0) : (Wupd + (c0 - DBX));

  float acc[4] = {0,0,0,0};
  {
    int k0 = ks*128;
    #pragma unroll 4
    for (int k=k0; k<k0+128; ++k){
      float a = hTn[k*BB + lane];
      float4 wa = *(const float4*)(wbase + (size_t)k*strd);
      acc[0]+=a*wa.x; acc[1]+=a*wa.y; acc[2]+=a*wa.z; acc[3]+=a*wa.w;
    }
  }
  #pragma unroll
  for (int u=0; u<4; ++u) part[ks][u][lane] = acc[u];
  __syncthreads();

  {
    int idx = tid;              // 256 = 4*BB exactly
    int u = idx>>6, b = idx&63;
    int c = c0+u;
    float v = part[0][u][b] + part[1][u][b] + part[2][u][b] + part[3][u][b];
    if (isout){
      out[((size_t)b*TT + t)*DBX + c] = sigmf(v + bout[c]);
    } else {
      int u2 = c - DBX;
      int hh = u2 / PPH;
      int p  = u2 - hh*PPH;
      v += bupd[u2];
      if (p < MMM)            kvec_t[b*HS + p*NH + hh] = v;
      else if (p == MMM)      beta[b*NH+hh] = softplusf(v);
      else if (p == MMM+1)    gbuf[b*NH+hh] = sigmf(v);
      else if (p <  MMM+5)    shraw[(b*NH+hh)*3 + (p-(MMM+2))] = v;
      else if (p == MMM+5)    gam[b*NH+hh] = 1.0f + softplusf(v);
      else if (p <  2*MMM+6)  erase[b*HS + hh*MMM + (p-(MMM+6))] = sigmf(v);
      else                    addb[b*HS + hh*MMM + (p-(2*MMM+6))] = tanhf(v);
    }
  }
}

// ---------------- dots partial: 32 m-rows per block (round-14 form) ----------------
__global__ __launch_bounds__(512) void k_dotsP(
    const float* __restrict__ mem, const float* __restrict__ kvec_t,
    float* __restrict__ dpart, float* __restrict__ n2part)
{
  int b = blockIdx.x, s = blockIdx.y, z = blockIdx.z, tid = threadIdx.x;
  __shared__ __align__(16) float klt[128];  // 32 rows x 4 heads, [m][h]
  if (tid < 128) klt[tid] = kvec_t[b*HS + z*128 + tid];
  __syncthreads();
  int a = s*512 + tid;
  const float* mp = mem + (size_t)b*MMM*AAA + (size_t)(z*32)*AAA + a;
  const float4* k4 = (const float4*)klt;
  float a0=0,a1=0,a2=0,a3=0,n2=0;
  #pragma unroll 8
  for (int m=0; m<32; ++m){
    float mv = mp[(size_t)m*AAA];
    float4 kv = k4[m];
    a0 += kv.x*mv; a1 += kv.y*mv; a2 += kv.z*mv; a3 += kv.w*mv;
    n2 += mv*mv;
  }
  size_t base = ((size_t)(z*BB+b)*NH)*AAA + a;
  dpart[base]        = a0;
  dpart[base+AAA]    = a1;
  dpart[base+2*AAA]  = a2;
  dpart[base+3*AAA]  = a3;
  n2part[(size_t)(z*BB+b)*AAA + a] = n2;
}

// ---------------- dots finalize: knorm + sim + exp + wcsum (round-14 form) ----------------
__global__ __launch_bounds__(512) void k_dotsF(
    const float* __restrict__ dpart, const float* __restrict__ n2part,
    const float* __restrict__ kvec_t, const float* __restrict__ beta,
    float* __restrict__ ebuf, float* __restrict__ wcsum)
{
  int b = blockIdx.x, s = blockIdx.y, tid = threadIdx.x;
  __shared__ float red[HS];
  __shared__ float kn[NH];
  __shared__ float rsum[8*NH];
  float kv = kvec_t[b*HS + tid];
  red[tid] = kv*kv;
  __syncthreads();
  #pragma unroll
  for (int off=256; off>=4; off>>=1){
    if (tid < off) red[tid] += red[tid+off];
    __syncthreads();
  }
  if (tid < NH) kn[tid] = sqrtf(red[tid]);
  __syncthreads();

  int a = s*512 + tid;
  float d[NH] = {0,0,0,0};
  float n2 = 0.0f;
  #pragma unroll
  for (int z=0; z<4; ++z){
    size_t base = ((size_t)(z*BB+b)*NH)*AAA + a;
    d[0] += dpart[base];
    d[1] += dpart[base+AAA];
    d[2] += dpart[base+2*AAA];
    d[3] += dpart[base+3*AAA];
    n2   += n2part[(size_t)(z*BB+b)*AAA + a];
  }
  float mn = sqrtf(n2);
  int wid = tid >> 6, lane = tid & 63;
  #pragma unroll
  for (int hh=0; hh<NH; ++hh){
    float sim = d[hh]/(kn[hh]*mn + EPSF);
    float e = expf(beta[b*NH+hh]*sim);
    ebuf[((size_t)(b*NH+hh))*AAA + a] = e;
    float v = e;
    #pragma unroll
    for (int off=32; off>0; off>>=1) v += __shfl_xor(v, off);
    if (lane==0) rsum[wid*NH+hh] = v;
  }
  __syncthreads();
  if (tid < NH){
    float s2 = 0.0f;
    #pragma unroll
    for (int w=0; w<8; ++w) s2 += rsum[w*NH+tid];
    atomicAdd(&wcsum[b*NH+tid], s2);
  }
}

// ---------------- normalize + interpolate + shift + sharpen (round-14 form) ----------------
__global__ __launch_bounds__(512) void k_shift(
    const float* __restrict__ ebuf, const float* __restrict__ wcsum,
    const float* __restrict__ gbuf, const float* __restrict__ shraw,
    const float* __restrict__ gam, const float* __restrict__ wt,
    float* __restrict__ wpb, float* __restrict__ wpsum)
{
  int b = blockIdx.x, s = blockIdx.y, tid = threadIdx.x;
  int a = s*512 + tid;
  int am1 = (a + AAA - 1) & (AAA-1);
  int ap1 = (a + 1) & (AAA-1);
  __shared__ float sh[NH*3], gl[NH], gml[NH], winv[NH];
  __shared__ float rsum[8*NH];
  if (tid < NH){
    int hh = tid;
    float s0=shraw[(b*NH+hh)*3], s1=shraw[(b*NH+hh)*3+1], s2=shraw[(b*NH+hh)*3+2];
    float mx = fmaxf(s0, fmaxf(s1, s2));
    float e0=expf(s0-mx), e1=expf(s1-mx), e2=expf(s2-mx);
    float inv = 1.0f/(e0+e1+e2);
    sh[hh*3+0]=e0*inv; sh[hh*3+1]=e1*inv; sh[hh*3+2]=e2*inv;
    gl[hh]  = gbuf[b*NH+hh];
    gml[hh] = gam[b*NH+hh];
    winv[hh]= 1.0f/wcsum[b*NH+hh];
  }
  __syncthreads();
  int wid = tid >> 6, lane = tid & 63;
  #pragma unroll
  for (int hh=0; hh<NH; ++hh){
    const float* eb = ebuf + ((size_t)(b*NH+hh))*AAA;
    const float* wb = wt   + ((size_t)(b*NH+hh))*AAA;
    float inv = winv[hh], g = gl[hh];
    float s0 = sh[hh*3+0], s1 = sh[hh*3+1], s2 = sh[hh*3+2];
    float wgm1 = g*eb[am1]*inv + (1.0f-g)*wb[am1];
    float wg0  = g*eb[a]  *inv + (1.0f-g)*wb[a];
    float wgp1 = g*eb[ap1]*inv + (1.0f-g)*wb[ap1];
    float ws = s0*wgp1 + s1*wg0 + s2*wgm1;
    float wp = powf(ws + EPSF, gml[hh]);
    wpb[((size_t)(b*NH+hh))*AAA + a] = wp;
    float v = wp;
    #pragma unroll
    for (int off=32; off>0; off>>=1) v += __shfl_xor(v, off);
    if (lane==0) rsum[wid*NH+hh] = v;
  }
  __syncthreads();
  if (tid < NH){
    float s3 = 0.0f;
    #pragma unroll
    for (int w=0; w<8; ++w) s3 += rsum[w*NH+tid];
    atomicAdd(&wpsum[b*NH+tid], s3);
  }
}

// ---------------- updAB: row-wise fused wt_new + mem erase/add + read einsum (round-14) ----------------
__global__ __launch_bounds__(512) void k_updAB(
    float* __restrict__ mem, const float* __restrict__ wpb, const float* __restrict__ wpsum,
    const float* __restrict__ erase, const float* __restrict__ addb,
    float* __restrict__ wt, float* __restrict__ readTn)
{
  __shared__ __align__(16) float wl[AAA*4];   // [a][h], 32 KB
  int b = blockIdx.x, my = blockIdx.y, tid = threadIdx.x;
  int wave = tid >> 6, lane = tid & 63;
  float winv[4];
  #pragma unroll
  for (int h=0;h<4;++h) winv[h] = 1.0f/wpsum[b*NH+h];
  // phase 0: wtn -> LDS (+ global wt, my==0 blocks only)
  #pragma unroll
  for (int c4=0;c4<4;++c4){
    int a = c4*512 + tid;
    float w0 = wpb[((size_t)(b*NH+0))*AAA + a]*winv[0];
    float w1 = wpb[((size_t)(b*NH+1))*AAA + a]*winv[1];
    float w2 = wpb[((size_t)(b*NH+2))*AAA + a]*winv[2];
    float w3 = wpb[((size_t)(b*NH+3))*AAA + a]*winv[3];
    wl[a*4+0]=w0; wl[a*4+1]=w1; wl[a*4+2]=w2; wl[a*4+3]=w3;
    if (my == 0){
      wt[((size_t)(b*NH+0))*AAA + a] = w0;
      wt[((size_t)(b*NH+1))*AAA + a] = w1;
      wt[((size_t)(b*NH+2))*AAA + a] = w2;
      wt[((size_t)(b*NH+3))*AAA + a] = w3;
    }
  }
  __syncthreads();

  int m0 = my*8 + wave, m1 = m0 + 64;
  float er0[4], ad0[4], er1[4], ad1[4];
  #pragma unroll
  for (int h=0;h<4;++h){
    er0[h] = erase[b*HS + h*MMM + m0];
    ad0[h] = addb [b*HS + h*MMM + m0];
    er1[h] = erase[b*HS + h*MMM + m1];
    ad1[h] = addb [b*HS + h*MMM + m1];
  }
  float* row0 = mem + (size_t)b*MMM*AAA + (size_t)m0*AAA;
  float* row1 = mem + (size_t)b*MMM*AAA + (size_t)m1*AAA;
  const float4* wl4 = (const float4*)wl;
  float r00=0,r01=0,r02=0,r03=0, r10=0,r11=0,r12=0,r13=0;
  #pragma unroll 4
  for (int it=0; it<32; ++it){
    int a = it*64 + lane;
    float mv0 = row0[a], mv1 = row1[a];
    float4 w4 = wl4[a];
    float et0 = (1.0f - er0[0]*w4.x)*(1.0f - er0[1]*w4.y)
              * (1.0f - er0[2]*w4.z)*(1.0f - er0[3]*w4.w);
    float at0 = ad0[0]*w4.x + ad0[1]*w4.y + ad0[2]*w4.z + ad0[3]*w4.w;
    float n0 = mv0*et0 + at0;
    row0[a] = n0;
    r00 += n0*w4.x; r01 += n0*w4.y; r02 += n0*w4.z; r03 += n0*w4.w;
    float et1 = (1.0f - er1[0]*w4.x)*(1.0f - er1[1]*w4.y)
              * (1.0f - er1[2]*w4.z)*(1.0f - er1[3]*w4.w);
    float at1 = ad1[0]*w4.x + ad1[1]*w4.y + ad1[2]*w4.z + ad1[3]*w4.w;
    float n1 = mv1*et1 + at1;
    row1[a] = n1;
    r10 += n1*w4.x; r11 += n1*w4.y; r12 += n1*w4.z; r13 += n1*w4.w;
  }
  float rr[2][NH] = {{r00,r01,r02,r03},{r10,r11,r12,r13}};
  #pragma unroll
  for (int q=0; q<2; ++q){
    #pragma unroll
    for (int hh=0; hh<NH; ++hh){
      float v = rr[q][hh];
      #pragma unroll
      for (int off=32; off>0; off>>=1) v += __shfl_xor(v, off);
      rr[q][hh] = v;
    }
  }
  if (lane == 0){
    #pragma unroll
    for (int hh=0; hh<NH; ++hh){
      readTn[(size_t)(hh*MMM+m0)*BB + b] = rr[0][hh];
      readTn[(size_t)(hh*MMM+m1)*BB + b] = rr[1][hh];
    }
  }
}

extern "C" void kernel_launch(void* const* d_in, const int* in_sizes, int n_in,
                              void* d_out, int out_size, void* d_ws, size_t ws_size,
                              hipStream_t stream){
  const float* x    = (const float*)d_in[0];
  const float* Wst  = (const float*)d_in[1];
  const float* bst  = (const float*)d_in[2];
  const float* Wout = (const float*)d_in[3];
  const float* bout = (const float*)d_in[4];
  const float* Wupd = (const float*)d_in[5];
  const float* bupd = (const float*)d_in[6];
  float* out = (float*)d_out;

  float* p = (float*)d_ws;
  float* hT     = p; p += 2*HS*BB;            // ping-pong h, [j][b]
  float* readT  = p; p += 2*HS*BB;            // ping-pong read, [(h,m)][b]
  float* hpart  = p; p += KSPL*HS*BB;         // split-K partials (2 MB)
  float* xT     = p; p += (size_t)TT*IND*BB;  // transposed x (8.65 MB)
  float* wt     = p; p += BB*NH*AAA;
  float* mem    = p; p += (size_t)BB*MMM*AAA;
  float* kvec_t = p; p += BB*HS;
  float* beta   = p; p += BB*NH;
  float* gbuf   = p; p += BB*NH;
  float* gam    = p; p += BB*NH;
  float* shraw  = p; p += BB*NH*3;
  float* erase  = p; p += BB*HS;
  float* addb   = p; p += BB*HS;
  float* ebuf   = p; p += BB*NH*AAA;
  float* wpb    = p; p += 4*(size_t)BB*NH*AAA; // 8.4 MB: doubles as k_dots dpart
  float* n2part = p; p += 4*BB*AAA;            // 2 MB
  float* wcsum  = p; p += BB*NH;
  float* wpsum  = p; p += BB*NH;
  float* dpart  = wpb;                         // alias: dpart consumed before wpb written

  k_init<<<2048, 256, 0, stream>>>(hT, readT, wt, mem);
  k_tx<<<BB, 256, 0, stream>>>(x, xT);
  for (int t=0; t<TT; ++t){
    const float* hTp = hT    + (t&1)*HS*BB;
    float* hTn       = hT    + ((t+1)&1)*HS*BB;
    const float* rTp = readT + (t&1)*HS*BB;
    float* rTn       = readT + ((t+1)&1)*HS*BB;
    k1_state<<<dim3(32,KSPL), 256, 0, stream>>>(xT, Wst, hTp, rTp, hpart, wcsum, wpsum, t);
    k2h<<<128, 256, 0, stream>>>(hpart, bst, hTn);
    k2_outupd<<<dim3(518), 256, 0, stream>>>(hTn, Wout, bout, Wupd, bupd, out,
        kvec_t, beta, gbuf, gam, shraw, erase, addb, t);
    k_dotsP<<<dim3(BB,4,4), 512, 0, stream>>>(mem, kvec_t, dpart, n2part);
    k_dotsF<<<dim3(BB,4), 512, 0, stream>>>(dpart, n2part, kvec_t, beta, ebuf, wcsum);
    k_shift<<<dim3(BB,4), 512, 0, stream>>>(ebuf, wcsum, gbuf, shraw, gam, wt, wpb, wpsum);
    k_updAB<<<dim3(BB,8), 512, 0, stream>>>(mem, wpb, wpsum, erase, addb, wt, rTn);
  }
}

// Round 17
// 9261.436 us; speedup vs baseline: 1.2301x; 1.0554x over previous
//
#include <hip/hip_runtime.h>
#include <math.h>

#define BB 64
#define TT 128
#define DBX 256
#define IND 264
#define HS 512
#define NH 4
#define MMM 128
#define AAA 2048
#define PPH 390
#define NCOLS (DBX + NH*PPH)   // 2072
#define KTOT (IND + HS + HS)   // 1288
#define KSPL 16                // k1 split-K: 16 x 81
#define KCH  81
#define EPSF 1e-8f

__device__ __forceinline__ float sigmf(float x){ return 1.0f/(1.0f+expf(-x)); }
__device__ __forceinline__ float softplusf(float x){ return (x > 20.0f) ? x : log1pf(expf(x)); }

// ---------------- init ----------------
__global__ void k_init(float* __restrict__ hT, float* __restrict__ readT,
                       float* __restrict__ wt, float* __restrict__ mem){
  int i = blockIdx.x*blockDim.x + threadIdx.x;
  int stride = gridDim.x*blockDim.x;
  for (int idx=i; idx<BB*MMM*AAA; idx+=stride) mem[idx]=0.01f;
  for (int idx=i; idx<HS*BB; idx+=stride){ hT[idx]=1.0f; readT[idx]=0.01f; }
  for (int idx=i; idx<BB*NH*AAA; idx+=stride) wt[idx] = ((idx & (AAA-1))==0)?1.0f:0.0f;
}

// ---------------- transpose x[b][t][i] -> xT[t*IND+i][b] (once) ----------------
__global__ __launch_bounds__(256) void k_tx(const float* __restrict__ x, float* __restrict__ xT){
  int b = blockIdx.x;
  for (int f = threadIdx.x; f < TT*IND; f += 256)
    xT[(size_t)f*BB + b] = x[(size_t)b*TT*IND + f];
}

// ---------------- k1: split-K partial GEMM  hpart[ks][j][b], 16-way ----------------
__global__ __launch_bounds__(256) void k1_state(
    const float* __restrict__ xT, const float* __restrict__ Wst,
    const float* __restrict__ hTp, const float* __restrict__ readTp,
    float* __restrict__ hpart, float* __restrict__ wcsum, float* __restrict__ wpsum, int t)
{
  int tid = threadIdx.x, wave = tid>>6, lane = tid&63;
  int ks = blockIdx.y;
  int j0 = blockIdx.x*16 + wave*4;
  if (blockIdx.x==0 && ks==0){
    wcsum[tid] = 0.0f;   // BB*NH == 256
    wpsum[tid] = 0.0f;
  }
  float a0=0,a1=0,a2=0,a3=0;
  int k0 = ks*KCH, kend = k0+KCH;
  if (kend > KTOT) kend = KTOT;

  #define K1STEP(AEXPR) { float aV=(AEXPR); \
      float4 wv = *(const float4*)(Wst + (size_t)k*HS + j0); \
      a0 += aV*wv.x; a1 += aV*wv.y; a2 += aV*wv.z; a3 += aV*wv.w; }

  {int s = k0, e = kend<IND?kend:IND;
   #pragma unroll 4
   for (int k=s;k<e;++k) K1STEP(xT[((size_t)t*IND + k)*BB + lane]); }
  {int s = k0>IND?k0:IND, e = kend<(IND+HS)?kend:(IND+HS);
   #pragma unroll 4
   for (int k=s;k<e;++k) K1STEP(hTp[(k-IND)*BB + lane]); }
  {int s = k0>(IND+HS)?k0:(IND+HS), e = kend;
   #pragma unroll 4
   for (int k=s;k<e;++k) K1STEP(readTp[(k-IND-HS)*BB + lane]); }
  #undef K1STEP

  float* hp = hpart + (size_t)ks*HS*BB + (size_t)j0*BB + lane;
  hp[0]    = a0;
  hp[BB]   = a1;
  hp[2*BB] = a2;
  hp[3*BB] = a3;
}

// ---------------- k2h: reduce 16 split-K partials -> h = sigmoid(. + b) ----------------
__global__ __launch_bounds__(256) void k2h(
    const float* __restrict__ hpart, const float* __restrict__ bst, float* __restrict__ hTn)
{
  int idx = blockIdx.x*256 + threadIdx.x;   // 128 blocks x 256 = 32768 = HS*BB
  float v = 0.0f;
  #pragma unroll
  for (int ks=0; ks<KSPL; ++ks) v += hpart[(size_t)ks*HS*BB + idx];
  hTn[idx] = sigmf(v + bst[idx>>6]);
}

// ---------------- k2: out/upd GEMM, 4 cols/block, split-K across 4 waves ----------------
// grid 518 blocks (518*4 = 2072 = NCOLS; blocks 0..63 are Wout, no straddle)
__global__ __launch_bounds__(256) void k2_outupd(
    const float* __restrict__ hTn,
    const float* __restrict__ Wout, const float* __restrict__ bout,
    const float* __restrict__ Wupd, const float* __restrict__ bupd,
    float* __restrict__ out,
    float* __restrict__ kvec_t, float* __restrict__ beta, float* __restrict__ gbuf,
    float* __restrict__ gam, float* __restrict__ shraw,
    float* __restrict__ erase, float* __restrict__ addb, int t)
{
  __shared__ float part[4][4][BB];
  int tid = threadIdx.x, ks = tid>>6, lane = tid&63;
  int c0 = blockIdx.x*4;
  bool isout = (c0 < DBX);
  size_t strd = isout ? (size_t)DBX : (size_t)(NH*PPH);
  const float* wbase = isout ? (Wout + c0) : (Wupd + (c0 - DBX));

  float acc[4] = {0,0,0,0};
  {
    int k0 = ks*128;
    #pragma unroll 4
    for (int k=k0; k<k0+128; ++k){
      float a = hTn[k*BB + lane];
      float4 wa = *(const float4*)(wbase + (size_t)k*strd);
      acc[0]+=a*wa.x; acc[1]+=a*wa.y; acc[2]+=a*wa.z; acc[3]+=a*wa.w;
    }
  }
  #pragma unroll
  for (int u=0; u<4; ++u) part[ks][u][lane] = acc[u];
  __syncthreads();

  {
    int idx = tid;              // 256 = 4*BB exactly
    int u = idx>>6, b = idx&63;
    int c = c0+u;
    float v = part[0][u][b] + part[1][u][b] + part[2][u][b] + part[3][u][b];
    if (isout){
      out[((size_t)b*TT + t)*DBX + c] = sigmf(v + bout[c]);
    } else {
      int u2 = c - DBX;
      int hh = u2 / PPH;
      int p  = u2 - hh*PPH;
      v += bupd[u2];
      if (p < MMM)            kvec_t[b*HS + p*NH + hh] = v;
      else if (p == MMM)      beta[b*NH+hh] = softplusf(v);
      else if (p == MMM+1)    gbuf[b*NH+hh] = sigmf(v);
      else if (p <  MMM+5)    shraw[(b*NH+hh)*3 + (p-(MMM+2))] = v;
      else if (p == MMM+5)    gam[b*NH+hh] = 1.0f + softplusf(v);
      else if (p <  2*MMM+6)  erase[b*HS + hh*MMM + (p-(MMM+6))] = sigmf(v);
      else                    addb[b*HS + hh*MMM + (p-(2*MMM+6))] = tanhf(v);
    }
  }
}

// ---------------- dots (fused, high-TLP): knorm + dot + mnorm + exp + wcsum ----------------
// grid (BB, 8), block 512. Block owns 256 cols; m-chain split 2-ways across thread halves
// (chain 64, 16-deep batches), LDS partner-combine. 512 blocks = 2/CU = 16 waves/CU.
__global__ __launch_bounds__(512) void k_dots(
    const float* __restrict__ mem, const float* __restrict__ kvec_t,
    const float* __restrict__ beta,
    float* __restrict__ ebuf, float* __restrict__ wcsum)
{
  int b = blockIdx.x, s = blockIdx.y, tid = threadIdx.x;
  __shared__ __align__(16) float kl[HS];    // [m*4+h]
  __shared__ float red[512];
  __shared__ float kn[NH], pb[NH];
  __shared__ float comb[256*5];             // partner combine: d0..d3,n2
  __shared__ float rs[8*NH];
  kl[tid] = kvec_t[b*HS + tid];
  if (tid < NH) pb[tid] = beta[b*NH + tid];
  __syncthreads();
  red[tid] = kl[tid]*kl[tid];
  __syncthreads();
  #pragma unroll
  for (int off=256; off>=4; off>>=1){
    if (tid < off) red[tid] += red[tid+off];
    __syncthreads();
  }
  if (tid < NH) kn[tid] = sqrtf(red[tid]);
  __syncthreads();

  int col = tid & 255;            // 0..255
  int mh  = tid >> 8;             // 0..1 (m-half)
  int a = s*256 + col;
  const float* mp = mem + (size_t)b*MMM*AAA + (size_t)(mh*64)*AAA + a;
  const float4* k4 = (const float4*)kl;
  float d0=0,d1=0,d2=0,d3=0,n2=0;
  for (int mb=0; mb<64; mb+=16){
    float mv[16];
    #pragma unroll
    for (int u=0;u<16;++u) mv[u] = mp[(size_t)(mb+u)*AAA];
    #pragma unroll
    for (int u=0;u<16;++u){
      float4 kv = k4[mh*64 + mb+u];
      d0 += kv.x*mv[u]; d1 += kv.y*mv[u]; d2 += kv.z*mv[u]; d3 += kv.w*mv[u];
      n2 += mv[u]*mv[u];
    }
  }
  if (mh){
    comb[col*5+0]=d0; comb[col*5+1]=d1; comb[col*5+2]=d2; comb[col*5+3]=d3; comb[col*5+4]=n2;
  }
  __syncthreads();
  float e_r[NH];
  if (!mh){
    d0 += comb[col*5+0]; d1 += comb[col*5+1]; d2 += comb[col*5+2]; d3 += comb[col*5+3];
    n2 += comb[col*5+4];
    float mn = sqrtf(n2);
    float dd[NH] = {d0,d1,d2,d3};
    #pragma unroll
    for (int hh=0; hh<NH; ++hh){
      float sim = dd[hh]/(kn[hh]*mn + EPSF);
      e_r[hh] = expf(pb[hh]*sim);
      ebuf[((size_t)(b*NH+hh))*AAA + a] = e_r[hh];
    }
  } else {
    #pragma unroll
    for (int hh=0; hh<NH; ++hh) e_r[hh] = 0.0f;
  }
  int wave = tid >> 6, lane = tid & 63;
  #pragma unroll
  for (int hh=0; hh<NH; ++hh){
    float v = e_r[hh];
    #pragma unroll
    for (int off=32; off>0; off>>=1) v += __shfl_xor(v, off);
    if (lane==0) rs[wave*NH+hh] = v;
  }
  __syncthreads();
  if (tid < NH){
    float s2 = 0.0f;
    #pragma unroll
    for (int w=0; w<8; ++w) s2 += rs[w*NH+tid];
    atomicAdd(&wcsum[b*NH+tid], s2);
  }
}

// ---------------- normalize + interpolate + shift + sharpen (round-14 form) ----------------
__global__ __launch_bounds__(512) void k_shift(
    const float* __restrict__ ebuf, const float* __restrict__ wcsum,
    const float* __restrict__ gbuf, const float* __restrict__ shraw,
    const float* __restrict__ gam, const float* __restrict__ wt,
    float* __restrict__ wpb, float* __restrict__ wpsum)
{
  int b = blockIdx.x, s = blockIdx.y, tid = threadIdx.x;
  int a = s*512 + tid;
  int am1 = (a + AAA - 1) & (AAA-1);
  int ap1 = (a + 1) & (AAA-1);
  __shared__ float sh[NH*3], gl[NH], gml[NH], winv[NH];
  __shared__ float rsum[8*NH];
  if (tid < NH){
    int hh = tid;
    float s0=shraw[(b*NH+hh)*3], s1=shraw[(b*NH+hh)*3+1], s2=shraw[(b*NH+hh)*3+2];
    float mx = fmaxf(s0, fmaxf(s1, s2));
    float e0=expf(s0-mx), e1=expf(s1-mx), e2=expf(s2-mx);
    float inv = 1.0f/(e0+e1+e2);
    sh[hh*3+0]=e0*inv; sh[hh*3+1]=e1*inv; sh[hh*3+2]=e2*inv;
    gl[hh]  = gbuf[b*NH+hh];
    gml[hh] = gam[b*NH+hh];
    winv[hh]= 1.0f/wcsum[b*NH+hh];
  }
  __syncthreads();
  int wid = tid >> 6, lane = tid & 63;
  #pragma unroll
  for (int hh=0; hh<NH; ++hh){
    const float* eb = ebuf + ((size_t)(b*NH+hh))*AAA;
    const float* wb = wt   + ((size_t)(b*NH+hh))*AAA;
    float inv = winv[hh], g = gl[hh];
    float s0 = sh[hh*3+0], s1 = sh[hh*3+1], s2 = sh[hh*3+2];
    float wgm1 = g*eb[am1]*inv + (1.0f-g)*wb[am1];
    float wg0  = g*eb[a]  *inv + (1.0f-g)*wb[a];
    float wgp1 = g*eb[ap1]*inv + (1.0f-g)*wb[ap1];
    float ws = s0*wgp1 + s1*wg0 + s2*wgm1;
    float wp = powf(ws + EPSF, gml[hh]);
    wpb[((size_t)(b*NH+hh))*AAA + a] = wp;
    float v = wp;
    #pragma unroll
    for (int off=32; off>0; off>>=1) v += __shfl_xor(v, off);
    if (lane==0) rsum[wid*NH+hh] = v;
  }
  __syncthreads();
  if (tid < NH){
    float s3 = 0.0f;
    #pragma unroll
    for (int w=0; w<8; ++w) s3 += rsum[w*NH+tid];
    atomicAdd(&wpsum[b*NH+tid], s3);
  }
}

// ---------------- updAB: row-wise fused wt_new + mem erase/add + read einsum (round-14) ----------------
__global__ __launch_bounds__(512) void k_updAB(
    float* __restrict__ mem, const float* __restrict__ wpb, const float* __restrict__ wpsum,
    const float* __restrict__ erase, const float* __restrict__ addb,
    float* __restrict__ wt, float* __restrict__ readTn)
{
  __shared__ __align__(16) float wl[AAA*4];   // [a][h], 32 KB
  int b = blockIdx.x, my = blockIdx.y, tid = threadIdx.x;
  int wave = tid >> 6, lane = tid & 63;
  float winv[4];
  #pragma unroll
  for (int h=0;h<4;++h) winv[h] = 1.0f/wpsum[b*NH+h];
  // phase 0: wtn -> LDS (+ global wt, my==0 blocks only)
  #pragma unroll
  for (int c4=0;c4<4;++c4){
    int a = c4*512 + tid;
    float w0 = wpb[((size_t)(b*NH+0))*AAA + a]*winv[0];
    float w1 = wpb[((size_t)(b*NH+1))*AAA + a]*winv[1];
    float w2 = wpb[((size_t)(b*NH+2))*AAA + a]*winv[2];
    float w3 = wpb[((size_t)(b*NH+3))*AAA + a]*winv[3];
    wl[a*4+0]=w0; wl[a*4+1]=w1; wl[a*4+2]=w2; wl[a*4+3]=w3;
    if (my == 0){
      wt[((size_t)(b*NH+0))*AAA + a] = w0;
      wt[((size_t)(b*NH+1))*AAA + a] = w1;
      wt[((size_t)(b*NH+2))*AAA + a] = w2;
      wt[((size_t)(b*NH+3))*AAA + a] = w3;
    }
  }
  __syncthreads();

  int m0 = my*8 + wave, m1 = m0 + 64;
  float er0[4], ad0[4], er1[4], ad1[4];
  #pragma unroll
  for (int h=0;h<4;++h){
    er0[h] = erase[b*HS + h*MMM + m0];
    ad0[h] = addb [b*HS + h*MMM + m0];
    er1[h] = erase[b*HS + h*MMM + m1];
    ad1[h] = addb [b*HS + h*MMM + m1];
  }
  float* row0 = mem + (size_t)b*MMM*AAA + (size_t)m0*AAA;
  float* row1 = mem + (size_t)b*MMM*AAA + (size_t)m1*AAA;
  const float4* wl4 = (const float4*)wl;
  float r00=0,r01=0,r02=0,r03=0, r10=0,r11=0,r12=0,r13=0;
  #pragma unroll 4
  for (int it=0; it<32; ++it){
    int a = it*64 + lane;
    float mv0 = row0[a], mv1 = row1[a];
    float4 w4 = wl4[a];
    float et0 = (1.0f - er0[0]*w4.x)*(1.0f - er0[1]*w4.y)
              * (1.0f - er0[2]*w4.z)*(1.0f - er0[3]*w4.w);
    float at0 = ad0[0]*w4.x + ad0[1]*w4.y + ad0[2]*w4.z + ad0[3]*w4.w;
    float n0 = mv0*et0 + at0;
    row0[a] = n0;
    r00 += n0*w4.x; r01 += n0*w4.y; r02 += n0*w4.z; r03 += n0*w4.w;
    float et1 = (1.0f - er1[0]*w4.x)*(1.0f - er1[1]*w4.y)
              * (1.0f - er1[2]*w4.z)*(1.0f - er1[3]*w4.w);
    float at1 = ad1[0]*w4.x + ad1[1]*w4.y + ad1[2]*w4.z + ad1[3]*w4.w;
    float n1 = mv1*et1 + at1;
    row1[a] = n1;
    r10 += n1*w4.x; r11 += n1*w4.y; r12 += n1*w4.z; r13 += n1*w4.w;
  }
  float rr[2][NH] = {{r00,r01,r02,r03},{r10,r11,r12,r13}};
  #pragma unroll
  for (int q=0; q<2; ++q){
    #pragma unroll
    for (int hh=0; hh<NH; ++hh){
      float v = rr[q][hh];
      #pragma unroll
      for (int off=32; off>0; off>>=1) v += __shfl_xor(v, off);
      rr[q][hh] = v;
    }
  }
  if (lane == 0){
    #pragma unroll
    for (int hh=0; hh<NH; ++hh){
      readTn[(size_t)(hh*MMM+m0)*BB + b] = rr[0][hh];
      readTn[(size_t)(hh*MMM+m1)*BB + b] = rr[1][hh];
    }
  }
}

extern "C" void kernel_launch(void* const* d_in, const int* in_sizes, int n_in,
                              void* d_out, int out_size, void* d_ws, size_t ws_size,
                              hipStream_t stream){
  const float* x    = (const float*)d_in[0];
  const float* Wst  = (const float*)d_in[1];
  const float* bst  = (const float*)d_in[2];
  const float* Wout = (const float*)d_in[3];
  const float* bout = (const float*)d_in[4];
  const float* Wupd = (const float*)d_in[5];
  const float* bupd = (const float*)d_in[6];
  float* out = (float*)d_out;

  float* p = (float*)d_ws;
  float* hT     = p; p += 2*HS*BB;            // ping-pong h, [j][b]
  float* readT  = p; p += 2*HS*BB;            // ping-pong read, [(h,m)][b]
  float* hpart  = p; p += KSPL*HS*BB;         // split-K partials (2 MB)
  float* xT     = p; p += (size_t)TT*IND*BB;  // transposed x (8.65 MB)
  float* wt     = p; p += BB*NH*AAA;
  float* mem    = p; p += (size_t)BB*MMM*AAA;
  float* kvec_t = p; p += BB*HS;
  float* beta   = p; p += BB*NH;
  float* gbuf   = p; p += BB*NH;
  float* gam    = p; p += BB*NH;
  float* shraw  = p; p += BB*NH*3;
  float* erase  = p; p += BB*HS;
  float* addb   = p; p += BB*HS;
  float* ebuf   = p; p += BB*NH*AAA;
  float* wpb    = p; p += BB*NH*AAA;           // 2 MB
  float* wcsum  = p; p += BB*NH;
  float* wpsum  = p; p += BB*NH;

  k_init<<<2048, 256, 0, stream>>>(hT, readT, wt, mem);
  k_tx<<<BB, 256, 0, stream>>>(x, xT);
  for (int t=0; t<TT; ++t){
    const float* hTp = hT    + (t&1)*HS*BB;
    float* hTn       = hT    + ((t+1)&1)*HS*BB;
    const float* rTp = readT + (t&1)*HS*BB;
    float* rTn       = readT + ((t+1)&1)*HS*BB;
    k1_state<<<dim3(32,KSPL), 256, 0, stream>>>(xT, Wst, hTp, rTp, hpart, wcsum, wpsum, t);
    k2h<<<128, 256, 0, stream>>>(hpart, bst, hTn);
    k2_outupd<<<dim3(518), 256, 0, stream>>>(hTn, Wout, bout, Wupd, bupd, out,
        kvec_t, beta, gbuf, gam, shraw, erase, addb, t);
    k_dots<<<dim3(BB,8), 512, 0, stream>>>(mem, kvec_t, beta, ebuf, wcsum);
    k_shift<<<dim3(BB,4), 512, 0, stream>>>(ebuf, wcsum, gbuf, shraw, gam, wt, wpb, wpsum);
    k_updAB<<<dim3(BB,8), 512, 0, stream>>>(mem, wpb, wpsum, erase, addb, wt, rTn);
  }
}